// Round 7
// baseline (143.461 us; speedup 1.0000x reference)
//
#include <hip/hip_runtime.h>

// Problem constants
#define B_    4
#define CIN_  64
#define COUT_ 64
#define H_    128
#define W_    128
#define HW_   (H_*W_)
#define K2_   9
#define NOFF_ 18

// padded NHWC fp16 tensor: rows -2..129 (132), cols -2..129 (132), 64 ch
#define PR_   132
#define PC_   132
#define PADY  2
#define PADX  2

// x tile in LDS: rows oh-2..oh+2, cols ow0-2..ow0+65
#define TROWS 5
#define TCOLS 68
#define CPAD  72    // LDS channel stride (halfs): 144B row -> bank base 4*t%32

typedef _Float16 f16x8 __attribute__((ext_vector_type(8)));  // MFMA A/B frag
typedef float    f32x4 __attribute__((ext_vector_type(4)));  // MFMA C/D

__device__ __forceinline__ f16x8 splat8(float f) {
    _Float16 h = (_Float16)f;
    return (f16x8){h, h, h, h, h, h, h, h};
}

// ---------------------------------------------------------------------------
// prep_all: one kernel for (a) interior NCHW fp32 -> padded NHWC fp16,
// (b) border zero-fill, (c) fp16 weight transforms (k-contiguous A-frags).
// Regions are disjoint: interior rows/cols 2..129; border rows {0,1,130,131}
// all cols; border cols {0,1,130,131} rows 2..129.
// ---------------------------------------------------------------------------
#define NB_INT    (B_ * H_)                 // 512 blocks: interior rows
#define ROWB_SEGS 16896                     // 4b * 4rows * 132cols * 8segs
#define BORD_SEGS (ROWB_SEGS + 16384)       // + 4b * 128rows * 4cols * 8segs
#define NB_BORD   ((BORD_SEGS + 255) / 256) // 130
#define NW_       (COUT_ * 576 + 32 * 576)  // 55296
#define NB_W      ((NW_ + 255) / 256)       // 216

__global__ __launch_bounds__(256) void prep_all(const float* __restrict__ x,
                                                const float* __restrict__ wd,
                                                const float* __restrict__ wo,
                                                _Float16* __restrict__ hx,
                                                _Float16* __restrict__ wt_b,
                                                _Float16* __restrict__ wt_ob) {
    const int bid = blockIdx.x, tid = threadIdx.x;
    if (bid < NB_INT) {
        // interior conversion: block = (b, y) row; thread = (xpos, c-half)
        int b = bid >> 7, y = bid & 127;
        int xp = tid & 127, ch = tid >> 7;
        const float* xs = x + ((b * CIN_ + ch * 32) * H_ + y) * W_ + xp;
        _Float16* hd = hx + (((size_t)b * PR_ + y + PADY) * PC_ + xp + PADX) * 64 + ch * 32;
        f16x8 h[4];
        #pragma unroll
        for (int j = 0; j < 4; ++j)
            #pragma unroll
            for (int t = 0; t < 8; ++t)
                h[j][t] = (_Float16)xs[(j * 8 + t) * HW_];
        #pragma unroll
        for (int j = 0; j < 4; ++j)
            *(f16x8*)(hd + j * 8) = h[j];
    } else if (bid < NB_INT + NB_BORD) {
        int s = (bid - NB_INT) * 256 + tid;
        f16x8 z = (f16x8){0, 0, 0, 0, 0, 0, 0, 0};
        if (s < ROWB_SEGS) {                 // border rows 0,1,130,131 (padded)
            int b = s / 4224, r2 = s % 4224;
            int yi = r2 / 1056, r3 = r2 % 1056;
            int col = r3 >> 3, seg = r3 & 7;
            int yp = (yi < 2) ? yi : 128 + yi;          // 0,1,130,131  (FIXED)
            *(f16x8*)(hx + (((size_t)b * PR_ + yp) * PC_ + col) * 64 + seg * 8) = z;
        } else if (s < BORD_SEGS) {          // border cols 0,1,130,131 for y 2..129
            int u = s - ROWB_SEGS;
            int b = u / 4096, r2 = u % 4096;
            int y = r2 >> 5, r3 = r2 & 31;
            int ci = r3 >> 3, seg = r3 & 7;
            int xp = (ci < 2) ? ci : 128 + ci;          // 0,1,130,131  (FIXED)
            *(f16x8*)(hx + (((size_t)b * PR_ + y + PADY) * PC_ + xp) * 64 + seg * 8) = z;
        }
    } else {
        int u = (bid - NB_INT - NB_BORD) * 256 + tid;
        if (u < COUT_ * 576) {
            int o = u / 576, rem = u % 576;
            int k2 = rem >> 6, c = rem & 63;
            wt_b[u] = (_Float16)wd[(o * CIN_ + c) * K2_ + k2];
        } else if (u < NW_) {
            int v = u - COUT_ * 576;
            int oc = v / 576, rem = v % 576;
            int k2 = rem >> 6, c = rem & 63;
            wt_ob[v] = (_Float16)((oc < NOFF_) ? wo[(oc * CIN_ + c) * K2_ + k2] : 0.f);
        }
    }
}

// ---------------------------------------------------------------------------
// deform_all: stage x tile -> offset conv (f16 MFMA) -> per-lane sampling
// directly into B-fragment registers -> deform f16 MFMA.
// Block = 64 px, 256 thr (4 waves), 3 blocks/CU. ONE __syncthreads total:
// wave cq owns pixels cq*16..cq*16+15 through offset conv, offsets LDS, and
// sampling, so all post-staging LDS traffic is wave-private.
// ---------------------------------------------------------------------------
__global__ __launch_bounds__(256, 3) void deform_all(const _Float16* __restrict__ hx,
                                                     const _Float16* __restrict__ wt_b,
                                                     const _Float16* __restrict__ wt_ob,
                                                     float* __restrict__ out) {
    __shared__ _Float16 xt[TROWS * TCOLS * CPAD];   // 47.8 KB
    __shared__ _Float16 offs_l[NOFF_ * 64];         // 2.25 KB

    const int tid = threadIdx.x;
    const int blk = blockIdx.x;            // (b*128 + oh)*2 + half
    const int b   = blk >> 8;
    const int r2  = blk & 255;
    const int oh  = r2 >> 1;
    const int ow0 = (r2 & 1) << 6;

    // ---- stage x tile: 2720 aligned 16B segments (tile base: padded row oh,
    // padded col ow0 == global (oh-2, ow0-2)) ----
    const _Float16* hrow = hx + (((size_t)b * PR_ + oh) * PC_ + ow0) * 64;
    for (int i = tid; i < TROWS * TCOLS * 8; i += 256) {
        int r   = i / (TCOLS * 8);
        int rem = i - r * (TCOLS * 8);
        int col = rem >> 3;
        int cs  = rem & 7;
        f16x8 v = *(const f16x8*)(hrow + ((size_t)r * PC_ + col) * 64 + cs * 8);
        *(f16x8*)&xt[(r * TCOLS + col) * CPAD + cs * 8] = v;
    }
    __syncthreads();     // the only block-wide barrier

    const int lane = tid & 63;
    const int cq   = tid >> 6;     // wave id; wave owns pixels cq*16..cq*16+15
    const int quad = lane >> 4;
    const int nl   = lane & 15;
    const int px   = cq * 16 + nl; // this lane's pixel (0..63 within row-half)
    const int ow   = ow0 + px;

    // ---- offset conv via f16 MFMA: out[32 oc][16 px per wave], K=576 ----
    f32x4 oacc[2];
    oacc[0] = (f32x4){0.f, 0.f, 0.f, 0.f};
    oacc[1] = (f32x4){0.f, 0.f, 0.f, 0.f};
    #pragma unroll
    for (int t9 = 0; t9 < 9; ++t9) {
        int ky = t9 / 3, kx = t9 - 3 * (t9 / 3);
        #pragma unroll
        for (int kb = 0; kb < 2; ++kb) {
            f16x8 bfr = *(const f16x8*)&xt[((ky + 1) * TCOLS + px + kx + 1) * CPAD + kb * 32 + quad * 8];
            #pragma unroll
            for (int mt = 0; mt < 2; ++mt) {
                f16x8 afr = *(const f16x8*)(wt_ob + (mt * 16 + nl) * 576 + t9 * 64 + kb * 32 + quad * 8);
                oacc[mt] = __builtin_amdgcn_mfma_f32_16x16x32_f16(afr, bfr, oacc[mt], 0, 0, 0);
            }
        }
    }
    // epilogue: C col = pixel nl (wave-local), row = mt*16+quad*4+r = oc
    #pragma unroll
    for (int mt = 0; mt < 2; ++mt)
        #pragma unroll
        for (int r = 0; r < 4; ++r) {
            int oc = mt * 16 + quad * 4 + r;
            if (oc < NOFF_) offs_l[oc * 64 + px] = (_Float16)oacc[mt][r];
        }
    __builtin_amdgcn_wave_barrier();   // order intra-wave LDS write -> read

    // ---- sampling into B-frags + deform MFMA (no barriers) ----
    f32x4 acc[4];
    #pragma unroll
    for (int mb = 0; mb < 4; ++mb) acc[mb] = (f32x4){0.f, 0.f, 0.f, 0.f};

    for (int k2 = 0; k2 < K2_; ++k2) {
        float dy = (float)offs_l[(2 * k2 + 0) * 64 + px];
        float dx = (float)offs_l[(2 * k2 + 1) * 64 + px];
        int ky = k2 / 3, kx = k2 - 3 * (k2 / 3);

        float py = (float)(oh - 1 + ky) + dy;
        float pxx = (float)(ow - 1 + kx) + dx;
        float y0f = floorf(py), x0f = floorf(pxx);
        float ly = py - y0f,    lx = pxx - x0f;
        int   y0 = (int)y0f,    x0 = (int)x0f;
        int   y1 = y0 + 1,      x1 = x0 + 1;

        float wy0 = 1.f - ly, wx0 = 1.f - lx;
        float w00 = wy0 * wx0, w01 = wy0 * lx, w10 = ly * wx0, w11 = ly * lx;

        bool vy0 = (unsigned)y0 < (unsigned)H_;
        bool vy1 = (unsigned)y1 < (unsigned)H_;
        bool vx0 = (unsigned)x0 < (unsigned)W_;
        bool vx1 = (unsigned)x1 < (unsigned)W_;
        if (!(vy0 & vx0)) w00 = 0.f;
        if (!(vy0 & vx1)) w01 = 0.f;
        if (!(vy1 & vx0)) w10 = 0.f;
        if (!(vy1 & vx1)) w11 = 0.f;

        f16x8 W00 = splat8(w00), W01 = splat8(w01), W10 = splat8(w10), W11 = splat8(w11);

        // tile coords (validity needed only when weight != 0)
        int ty0 = y0 - (oh - 2), ty1 = y1 - (oh - 2);
        int tx0 = x0 - (ow0 - 2), tx1 = x1 - (ow0 - 2);
        bool i00 = (unsigned)ty0 < TROWS && (unsigned)tx0 < TCOLS;
        bool i01 = (unsigned)ty0 < TROWS && (unsigned)tx1 < TCOLS;
        bool i10 = (unsigned)ty1 < TROWS && (unsigned)tx0 < TCOLS;
        bool i11 = (unsigned)ty1 < TROWS && (unsigned)tx1 < TCOLS;
        bool ok = (w00 == 0.f || i00) && (w01 == 0.f || i01) &&
                  (w10 == 0.f || i10) && (w11 == 0.f || i11);

        // this lane's channels: kb*32 + quad*8 + [0..8) -> B-frag registers
        f16x8 bfr0, bfr1;
        if (ok) {
            int tyc0 = min(max(ty0, 0), TROWS - 1), tyc1 = min(max(ty1, 0), TROWS - 1);
            int txc0 = min(max(tx0, 0), TCOLS - 1), txc1 = min(max(tx1, 0), TCOLS - 1);
            int a00 = (tyc0 * TCOLS + txc0) * CPAD + quad * 8;
            int a01 = (tyc0 * TCOLS + txc1) * CPAD + quad * 8;
            int a10 = (tyc1 * TCOLS + txc0) * CPAD + quad * 8;
            int a11 = (tyc1 * TCOLS + txc1) * CPAD + quad * 8;
            bfr0 = (*(const f16x8*)&xt[a00]) * W00 + (*(const f16x8*)&xt[a01]) * W01 +
                   (*(const f16x8*)&xt[a10]) * W10 + (*(const f16x8*)&xt[a11]) * W11;
            bfr1 = (*(const f16x8*)&xt[a00 + 32]) * W00 + (*(const f16x8*)&xt[a01 + 32]) * W01 +
                   (*(const f16x8*)&xt[a10 + 32]) * W10 + (*(const f16x8*)&xt[a11 + 32]) * W11;
        } else {
            // rare fallback: image-clamped gather from padded hx (global, L2)
            int y0c = min(max(y0, 0), H_ - 1), y1c = min(max(y1, 0), H_ - 1);
            int x0c = min(max(x0, 0), W_ - 1), x1c = min(max(x1, 0), W_ - 1);
            const _Float16* hb = hx + (size_t)b * PR_ * PC_ * 64 + quad * 8;
            const _Float16* g00 = hb + (((size_t)(y0c + PADY) * PC_) + x0c + PADX) * 64;
            const _Float16* g01 = hb + (((size_t)(y0c + PADY) * PC_) + x1c + PADX) * 64;
            const _Float16* g10 = hb + (((size_t)(y1c + PADY) * PC_) + x0c + PADX) * 64;
            const _Float16* g11 = hb + (((size_t)(y1c + PADY) * PC_) + x1c + PADX) * 64;
            bfr0 = (*(const f16x8*)g00) * W00 + (*(const f16x8*)g01) * W01 +
                   (*(const f16x8*)g10) * W10 + (*(const f16x8*)g11) * W11;
            bfr1 = (*(const f16x8*)(g00 + 32)) * W00 + (*(const f16x8*)(g01 + 32)) * W01 +
                   (*(const f16x8*)(g10 + 32)) * W10 + (*(const f16x8*)(g11 + 32)) * W11;
        }

        #pragma unroll
        for (int mb = 0; mb < 4; ++mb) {
            f16x8 afr0 = *(const f16x8*)(wt_b + (mb * 16 + nl) * 576 + k2 * 64 + quad * 8);
            acc[mb] = __builtin_amdgcn_mfma_f32_16x16x32_f16(afr0, bfr0, acc[mb], 0, 0, 0);
        }
        #pragma unroll
        for (int mb = 0; mb < 4; ++mb) {
            f16x8 afr1 = *(const f16x8*)(wt_b + (mb * 16 + nl) * 576 + k2 * 64 + 32 + quad * 8);
            acc[mb] = __builtin_amdgcn_mfma_f32_16x16x32_f16(afr1, bfr1, acc[mb], 0, 0, 0);
        }
    }

    // epilogue: C/D col = pixel (nl), row = quad*4 + r (verified layout)
    #pragma unroll
    for (int mb = 0; mb < 4; ++mb)
        #pragma unroll
        for (int r = 0; r < 4; ++r) {
            int o = mb * 16 + quad * 4 + r;
            out[(b * COUT_ + o) * HW_ + oh * W_ + ow0 + cq * 16 + nl] = acc[mb][r];
        }
}

// ---------------------------------------------------------------------------
extern "C" void kernel_launch(void* const* d_in, const int* in_sizes, int n_in,
                              void* d_out, int out_size, void* d_ws, size_t ws_size,
                              hipStream_t stream) {
    const float* x        = (const float*)d_in[0];  // (4, 64, 128, 128)
    const float* w_offset = (const float*)d_in[1];  // (18, 64, 3, 3)
    const float* w_deform = (const float*)d_in[2];  // (64, 64, 3, 3)
    float* out = (float*)d_out;                     // (4, 64, 128, 128)

    _Float16* hx    = (_Float16*)d_ws;                        // 4*132*132*64 halfs (8.9 MB)
    _Float16* wt_b  = hx + (size_t)B_ * PR_ * PC_ * 64;       // 64*576
    _Float16* wt_ob = wt_b + (size_t)COUT_ * 576;             // 32*576

    prep_all<<<NB_INT + NB_BORD + NB_W, 256, 0, stream>>>(x, w_deform, w_offset, hx, wt_b, wt_ob);
    deform_all<<<B_ * H_ * (W_ / 64), 256, 0, stream>>>(hx, wt_b, wt_ob, out);
}

// Round 10
// 141.474 us; speedup vs baseline: 1.0140x; 1.0140x over previous
//
#include <hip/hip_runtime.h>

// Problem constants
#define B_    4
#define CIN_  64
#define COUT_ 64
#define H_    128
#define W_    128
#define HW_   (H_*W_)
#define K2_   9
#define NOFF_ 18

// padded NHWC fp16 tensor: rows -2..129 (132), cols -2..129 (132), 64 ch
#define PR_   132
#define PC_   132
#define PADY  2
#define PADX  2

// x tile in LDS: rows oh-2..oh+2, cols ow0-2..ow0+65
#define TROWS 5
#define TCOLS 68
#define CPAD  72    // LDS channel stride (halfs): 144B row -> 2-way bank alias max

typedef _Float16 f16x8 __attribute__((ext_vector_type(8)));  // MFMA A/B frag
typedef float    f32x4 __attribute__((ext_vector_type(4)));  // MFMA C/D

__device__ __forceinline__ f16x8 splat8(float f) {
    _Float16 h = (_Float16)f;
    return (f16x8){h, h, h, h, h, h, h, h};
}

// ---------------------------------------------------------------------------
// prep_all v2 (THE ONLY CHANGE vs passing R7): interior NCHW fp32 -> padded
// NHWC fp16 via xor-swizzled LDS transpose, so global stores are contiguous
// (R7's direct stores were 16B at 128B lane stride = 64 lines/instr, ~60 µs).
// Border fill + weight transforms unchanged from R7. Regions disjoint.
// ---------------------------------------------------------------------------
#define NB_INT    (B_ * H_)                 // 512 blocks: interior rows
#define ROWB_SEGS 16896                     // 4b * 4rows * 132cols * 8segs
#define BORD_SEGS (ROWB_SEGS + 16384)       // + 4b * 128rows * 4cols * 8segs
#define NB_BORD   ((BORD_SEGS + 255) / 256) // 130
#define NW_       (COUT_ * 576 + 32 * 576)  // 55296
#define NB_W      ((NW_ + 255) / 256)       // 216

__global__ __launch_bounds__(256) void prep_all(const float* __restrict__ x,
                                                const float* __restrict__ wd,
                                                const float* __restrict__ wo,
                                                _Float16* __restrict__ hx,
                                                _Float16* __restrict__ wt_b,
                                                _Float16* __restrict__ wt_ob) {
    __shared__ _Float16 tb[128 * 72];       // 18.4 KB transpose buffer
    const int bid = blockIdx.x, tid = threadIdx.x;
    if (bid < NB_INT) {
        // phase A: coalesced NCHW reads -> LDS [xp][c] (xor-swizzled 16B slots)
        int b = bid >> 7, y = bid & 127;
        int xp = tid & 127, ch = tid >> 7;   // ch: 0/1 -> channels 0-31/32-63
        const float* xs = x + ((b * CIN_ + ch * 32) * H_ + y) * W_ + xp;
        #pragma unroll
        for (int j = 0; j < 4; ++j) {
            f16x8 h;
            #pragma unroll
            for (int t = 0; t < 8; ++t)
                h[t] = (_Float16)xs[(j * 8 + t) * HW_];
            int cseg = ch * 4 + j;                       // channel segment 0..7
            *(f16x8*)&tb[xp * 72 + (cseg ^ (xp & 7)) * 8] = h;
        }
        __syncthreads();
        // phase B: contiguous NHWC stores (16 KB per row, fully coalesced)
        _Float16* hd = hx + (((size_t)b * PR_ + y + PADY) * PC_ + PADX) * 64;
        #pragma unroll
        for (int it = 0; it < 4; ++it) {
            int id  = it * 256 + tid;                    // 0..1023
            int xp2 = id >> 3, seg = id & 7;
            f16x8 v = *(const f16x8*)&tb[xp2 * 72 + seg * 8];
            *(f16x8*)(hd + (size_t)xp2 * 64 + (seg ^ (xp2 & 7)) * 8) = v;
        }
    } else if (bid < NB_INT + NB_BORD) {
        int s = (bid - NB_INT) * 256 + tid;
        f16x8 z = (f16x8){0, 0, 0, 0, 0, 0, 0, 0};
        if (s < ROWB_SEGS) {                 // border rows 0,1,130,131 (padded)
            int b = s / 4224, r2 = s % 4224;
            int yi = r2 / 1056, r3 = r2 % 1056;
            int col = r3 >> 3, seg = r3 & 7;
            int yp = (yi < 2) ? yi : 128 + yi;           // 0,1,130,131
            *(f16x8*)(hx + (((size_t)b * PR_ + yp) * PC_ + col) * 64 + seg * 8) = z;
        } else if (s < BORD_SEGS) {          // border cols 0,1,130,131 for y 2..129
            int u = s - ROWB_SEGS;
            int b = u / 4096, r2 = u % 4096;
            int y = r2 >> 5, r3 = r2 & 31;
            int ci = r3 >> 3, seg = r3 & 7;
            int xp = (ci < 2) ? ci : 128 + ci;           // 0,1,130,131
            *(f16x8*)(hx + (((size_t)b * PR_ + y + PADY) * PC_ + xp) * 64 + seg * 8) = z;
        }
    } else {
        int u = (bid - NB_INT - NB_BORD) * 256 + tid;
        if (u < COUT_ * 576) {
            int o = u / 576, rem = u % 576;
            int k2 = rem >> 6, c = rem & 63;
            wt_b[u] = (_Float16)wd[(o * CIN_ + c) * K2_ + k2];
        } else if (u < NW_) {
            int v = u - COUT_ * 576;
            int oc = v / 576, rem = v % 576;
            int k2 = rem >> 6, c = rem & 63;
            wt_ob[v] = (_Float16)((oc < NOFF_) ? wo[(oc * CIN_ + c) * K2_ + k2] : 0.f);
        }
    }
}

// ---------------------------------------------------------------------------
// deform_all: VERBATIM the R7 kernel that passed at 72 µs (wave owns its 16
// pixels end-to-end; per-lane sampling directly into B-fragment registers;
// one __syncthreads total). Do not touch — known good.
// ---------------------------------------------------------------------------
__global__ __launch_bounds__(256, 3) void deform_all(const _Float16* __restrict__ hx,
                                                     const _Float16* __restrict__ wt_b,
                                                     const _Float16* __restrict__ wt_ob,
                                                     float* __restrict__ out) {
    __shared__ _Float16 xt[TROWS * TCOLS * CPAD];   // 47.8 KB
    __shared__ _Float16 offs_l[NOFF_ * 64];         // 2.25 KB

    const int tid = threadIdx.x;
    const int blk = blockIdx.x;            // (b*128 + oh)*2 + half
    const int b   = blk >> 8;
    const int r2  = blk & 255;
    const int oh  = r2 >> 1;
    const int ow0 = (r2 & 1) << 6;

    // ---- stage x tile ----
    const _Float16* hrow = hx + (((size_t)b * PR_ + oh) * PC_ + ow0) * 64;
    for (int i = tid; i < TROWS * TCOLS * 8; i += 256) {
        int r   = i / (TCOLS * 8);
        int rem = i - r * (TCOLS * 8);
        int col = rem >> 3;
        int cs  = rem & 7;
        f16x8 v = *(const f16x8*)(hrow + ((size_t)r * PC_ + col) * 64 + cs * 8);
        *(f16x8*)&xt[(r * TCOLS + col) * CPAD + cs * 8] = v;
    }
    __syncthreads();     // the only block-wide barrier

    const int lane = tid & 63;
    const int cq   = tid >> 6;     // wave id; wave owns pixels cq*16..cq*16+15
    const int quad = lane >> 4;
    const int nl   = lane & 15;
    const int px   = cq * 16 + nl; // this lane's pixel (0..63 within row-half)
    const int ow   = ow0 + px;

    // ---- offset conv via f16 MFMA: out[32 oc][16 px per wave], K=576 ----
    f32x4 oacc[2];
    oacc[0] = (f32x4){0.f, 0.f, 0.f, 0.f};
    oacc[1] = (f32x4){0.f, 0.f, 0.f, 0.f};
    #pragma unroll
    for (int t9 = 0; t9 < 9; ++t9) {
        int ky = t9 / 3, kx = t9 - 3 * (t9 / 3);
        #pragma unroll
        for (int kb = 0; kb < 2; ++kb) {
            f16x8 bfr = *(const f16x8*)&xt[((ky + 1) * TCOLS + px + kx + 1) * CPAD + kb * 32 + quad * 8];
            #pragma unroll
            for (int mt = 0; mt < 2; ++mt) {
                f16x8 afr = *(const f16x8*)(wt_ob + (mt * 16 + nl) * 576 + t9 * 64 + kb * 32 + quad * 8);
                oacc[mt] = __builtin_amdgcn_mfma_f32_16x16x32_f16(afr, bfr, oacc[mt], 0, 0, 0);
            }
        }
    }
    // epilogue: C col = pixel nl (wave-local), row = mt*16+quad*4+r = oc
    #pragma unroll
    for (int mt = 0; mt < 2; ++mt)
        #pragma unroll
        for (int r = 0; r < 4; ++r) {
            int oc = mt * 16 + quad * 4 + r;
            if (oc < NOFF_) offs_l[oc * 64 + px] = (_Float16)oacc[mt][r];
        }
    __builtin_amdgcn_wave_barrier();   // order intra-wave LDS write -> read

    // ---- sampling into B-frags + deform MFMA (no barriers) ----
    f32x4 acc[4];
    #pragma unroll
    for (int mb = 0; mb < 4; ++mb) acc[mb] = (f32x4){0.f, 0.f, 0.f, 0.f};

    for (int k2 = 0; k2 < K2_; ++k2) {
        float dy = (float)offs_l[(2 * k2 + 0) * 64 + px];
        float dx = (float)offs_l[(2 * k2 + 1) * 64 + px];
        int ky = k2 / 3, kx = k2 - 3 * (k2 / 3);

        float py = (float)(oh - 1 + ky) + dy;
        float pxx = (float)(ow - 1 + kx) + dx;
        float y0f = floorf(py), x0f = floorf(pxx);
        float ly = py - y0f,    lx = pxx - x0f;
        int   y0 = (int)y0f,    x0 = (int)x0f;
        int   y1 = y0 + 1,      x1 = x0 + 1;

        float wy0 = 1.f - ly, wx0 = 1.f - lx;
        float w00 = wy0 * wx0, w01 = wy0 * lx, w10 = ly * wx0, w11 = ly * lx;

        bool vy0 = (unsigned)y0 < (unsigned)H_;
        bool vy1 = (unsigned)y1 < (unsigned)H_;
        bool vx0 = (unsigned)x0 < (unsigned)W_;
        bool vx1 = (unsigned)x1 < (unsigned)W_;
        if (!(vy0 & vx0)) w00 = 0.f;
        if (!(vy0 & vx1)) w01 = 0.f;
        if (!(vy1 & vx0)) w10 = 0.f;
        if (!(vy1 & vx1)) w11 = 0.f;

        f16x8 W00 = splat8(w00), W01 = splat8(w01), W10 = splat8(w10), W11 = splat8(w11);

        // tile coords (validity needed only when weight != 0)
        int ty0 = y0 - (oh - 2), ty1 = y1 - (oh - 2);
        int tx0 = x0 - (ow0 - 2), tx1 = x1 - (ow0 - 2);
        bool i00 = (unsigned)ty0 < TROWS && (unsigned)tx0 < TCOLS;
        bool i01 = (unsigned)ty0 < TROWS && (unsigned)tx1 < TCOLS;
        bool i10 = (unsigned)ty1 < TROWS && (unsigned)tx0 < TCOLS;
        bool i11 = (unsigned)ty1 < TROWS && (unsigned)tx1 < TCOLS;
        bool ok = (w00 == 0.f || i00) && (w01 == 0.f || i01) &&
                  (w10 == 0.f || i10) && (w11 == 0.f || i11);

        // this lane's channels: kb*32 + quad*8 + [0..8) -> B-frag registers
        f16x8 bfr0, bfr1;
        if (ok) {
            int tyc0 = min(max(ty0, 0), TROWS - 1), tyc1 = min(max(ty1, 0), TROWS - 1);
            int txc0 = min(max(tx0, 0), TCOLS - 1), txc1 = min(max(tx1, 0), TCOLS - 1);
            int a00 = (tyc0 * TCOLS + txc0) * CPAD + quad * 8;
            int a01 = (tyc0 * TCOLS + txc1) * CPAD + quad * 8;
            int a10 = (tyc1 * TCOLS + txc0) * CPAD + quad * 8;
            int a11 = (tyc1 * TCOLS + txc1) * CPAD + quad * 8;
            bfr0 = (*(const f16x8*)&xt[a00]) * W00 + (*(const f16x8*)&xt[a01]) * W01 +
                   (*(const f16x8*)&xt[a10]) * W10 + (*(const f16x8*)&xt[a11]) * W11;
            bfr1 = (*(const f16x8*)&xt[a00 + 32]) * W00 + (*(const f16x8*)&xt[a01 + 32]) * W01 +
                   (*(const f16x8*)&xt[a10 + 32]) * W10 + (*(const f16x8*)&xt[a11 + 32]) * W11;
        } else {
            // rare fallback: image-clamped gather from padded hx (global, L2)
            int y0c = min(max(y0, 0), H_ - 1), y1c = min(max(y1, 0), H_ - 1);
            int x0c = min(max(x0, 0), W_ - 1), x1c = min(max(x1, 0), W_ - 1);
            const _Float16* hb = hx + (size_t)b * PR_ * PC_ * 64 + quad * 8;
            const _Float16* g00 = hb + (((size_t)(y0c + PADY) * PC_) + x0c + PADX) * 64;
            const _Float16* g01 = hb + (((size_t)(y0c + PADY) * PC_) + x1c + PADX) * 64;
            const _Float16* g10 = hb + (((size_t)(y1c + PADY) * PC_) + x0c + PADX) * 64;
            const _Float16* g11 = hb + (((size_t)(y1c + PADY) * PC_) + x1c + PADX) * 64;
            bfr0 = (*(const f16x8*)g00) * W00 + (*(const f16x8*)g01) * W01 +
                   (*(const f16x8*)g10) * W10 + (*(const f16x8*)g11) * W11;
            bfr1 = (*(const f16x8*)(g00 + 32)) * W00 + (*(const f16x8*)(g01 + 32)) * W01 +
                   (*(const f16x8*)(g10 + 32)) * W10 + (*(const f16x8*)(g11 + 32)) * W11;
        }

        #pragma unroll
        for (int mb = 0; mb < 4; ++mb) {
            f16x8 afr0 = *(const f16x8*)(wt_b + (mb * 16 + nl) * 576 + k2 * 64 + quad * 8);
            acc[mb] = __builtin_amdgcn_mfma_f32_16x16x32_f16(afr0, bfr0, acc[mb], 0, 0, 0);
        }
        #pragma unroll
        for (int mb = 0; mb < 4; ++mb) {
            f16x8 afr1 = *(const f16x8*)(wt_b + (mb * 16 + nl) * 576 + k2 * 64 + 32 + quad * 8);
            acc[mb] = __builtin_amdgcn_mfma_f32_16x16x32_f16(afr1, bfr1, acc[mb], 0, 0, 0);
        }
    }

    // epilogue: C/D col = pixel (nl), row = quad*4 + r (verified layout)
    #pragma unroll
    for (int mb = 0; mb < 4; ++mb)
        #pragma unroll
        for (int r = 0; r < 4; ++r) {
            int o = mb * 16 + quad * 4 + r;
            out[(b * COUT_ + o) * HW_ + oh * W_ + ow0 + cq * 16 + nl] = acc[mb][r];
        }
}

// ---------------------------------------------------------------------------
extern "C" void kernel_launch(void* const* d_in, const int* in_sizes, int n_in,
                              void* d_out, int out_size, void* d_ws, size_t ws_size,
                              hipStream_t stream) {
    const float* x        = (const float*)d_in[0];  // (4, 64, 128, 128)
    const float* w_offset = (const float*)d_in[1];  // (18, 64, 3, 3)
    const float* w_deform = (const float*)d_in[2];  // (64, 64, 3, 3)
    float* out = (float*)d_out;                     // (4, 64, 128, 128)

    _Float16* hx    = (_Float16*)d_ws;                        // 4*132*132*64 halfs (8.9 MB)
    _Float16* wt_b  = hx + (size_t)B_ * PR_ * PC_ * 64;       // 64*576
    _Float16* wt_ob = wt_b + (size_t)COUT_ * 576;             // 32*576

    prep_all<<<NB_INT + NB_BORD + NB_W, 256, 0, stream>>>(x, w_deform, w_offset, hx, wt_b, wt_ob);
    deform_all<<<B_ * H_ * (W_ / 64), 256, 0, stream>>>(hx, wt_b, wt_ob, out);
}